// Round 17
// baseline (3453.804 us; speedup 1.0000x reference)
//
#include <hip/hip_runtime.h>
#include <hip/hip_bf16.h>

// Problem dims
#define T_DIM 256
#define B_DIM 64
#define I_DIM 512
#define H_DIM 1024
#define U_DIM 8
#define BN_EPS 1e-5f
#define BH (B_DIM * H_DIM)
#define NCHUNK 64          // 4 timesteps per chunk
#define TILES_PER_CHUNK 80 // 16 zx + 64 s
#define NTILES 5120        // 64 chunks * 80

typedef __bf16 bf16x8 __attribute__((ext_vector_type(8)));
typedef float f32x4 __attribute__((ext_vector_type(4)));
typedef int i32x4 __attribute__((ext_vector_type(4)));
typedef unsigned short u16;
typedef u16 u16x4 __attribute__((ext_vector_type(4)));
typedef unsigned long long u64;
using bf16 = __hip_bfloat16;

// ---------------- conversion / packing kernels (vectorized) ----------------

__global__ void k_cvt4(const float* __restrict__ in, u16* __restrict__ out, int n4) {
    int i = blockIdx.x * blockDim.x + threadIdx.x;
    int stride = gridDim.x * blockDim.x;
    for (; i < n4; i += stride) {
        f32x4 v = *reinterpret_cast<const f32x4*>(in + (size_t)i * 4);
        u16x4 o;
#pragma unroll
        for (int j = 0; j < 4; ++j)
            o[j] = __bfloat16_as_ushort(__float2bfloat16(v[j]));
        *reinterpret_cast<u16x4*>(out + (size_t)i * 4) = o;
    }
}

// pack [Uz; Uh] into one [2048,1024] bf16 K-major matrix (4-elem chunks)
__global__ void k_pack_uzuh(const float* __restrict__ Uz, const float* __restrict__ Uh,
                            u16* __restrict__ out) {
    int i = blockIdx.x * 256 + threadIdx.x;
    int stride = gridDim.x * 256;
    int n4 = 2 * H_DIM * H_DIM / 4;
    for (; i < n4; i += stride) {
        int c = i * 4;
        int n = c >> 10, k = c & 1023;
        const float* src = (n < H_DIM) ? (Uz + (size_t)n * H_DIM + k)
                                       : (Uh + (size_t)(n - H_DIM) * H_DIM + k);
        f32x4 v = *reinterpret_cast<const f32x4*>(src);
        u16x4 o;
#pragma unroll
        for (int j = 0; j < 4; ++j)
            o[j] = __bfloat16_as_ushort(__float2bfloat16(v[j]));
        *reinterpret_cast<u16x4*>(out + c) = o;
    }
}

// extract block-diagonal of Wm = Wh_in * mask: wdiag[h*8+u] = Wm[h][h*8+u]
__global__ void k_wdiag(const float* __restrict__ Wh_in, const float* __restrict__ mask,
                        float* __restrict__ wdiag) {
    int idx = blockIdx.x * 256 + threadIdx.x;
    if (idx < H_DIM * U_DIM) {
        int h = idx >> 3;
        size_t col = (size_t)h * (H_DIM * U_DIM) + idx;
        wdiag[idx] = Wh_in[col] * mask[col];
    }
}

// fill h buffers with tagged -0.0 (0x8000): tag=1, strips to h0=0
__global__ void k_init_tag(u64* __restrict__ p, int n) {
    int i = blockIdx.x * 256 + threadIdx.x;
    if (i < n) p[i] = 0x8000800080008000ull;
}

// load 8 consecutive f32, convert to bf16x8 in-register (same RTN as k_cvt4)
__device__ __forceinline__ bf16x8 cvt8(const float* p) {
    f32x4 a = *reinterpret_cast<const f32x4*>(p);
    f32x4 b = *reinterpret_cast<const f32x4*>(p + 4);
    union { u16 u[8]; bf16x8 v; } r;
#pragma unroll
    for (int j = 0; j < 4; ++j) {
        r.u[j]     = __bfloat16_as_ushort(__float2bfloat16(a[j]));
        r.u[4 + j] = __bfloat16_as_ushort(__float2bfloat16(b[j]));
    }
    return r.v;
}

// ==================== MEGA KERNEL ====================
// 256 blocks x 512 threads (static roles; NO placement assumptions).
//  blocks 0..63: scan (4 cohorts x 16 blocks). DATA-AS-FLAG protocol:
//    h >= 0 always (h0=0, hu=relu>=0, z in (0,1)) => published bf16 sign bit
//    is a free tag. Publisher at step t sign-tags each element with (t>>1)&1
//    and publishes via RETURNING atomic swap (LLC, R11-proven). Consumer at
//    step t poll-loads the fragments (sc0 sc1, R10-proven) until all sign
//    bits match ((t-1)>>1)&1 (t=0 expects 1; buffers pre-init to 0x8000),
//    then strips signs. Stale (t-2) data always has the OPPOSITE tag.
//    => no flag array, no flag RTs, ONE barrier/step (LDS RED parity-
//    double-buffered). WAR safety flows through the data dependency chain.
//  blocks 64..255: persistent producers (R7 verbatim), release-atomicAdd done.

__global__ __launch_bounds__(512, 2) void k_mega(
    const float* __restrict__ x,
    const bf16* __restrict__ wzx, const bf16* __restrict__ whx,
    const float* __restrict__ b_unit, const float* __restrict__ wdiag,
    const float* __restrict__ gzp, const float* __restrict__ bzp,
    const float* __restrict__ ghp, const float* __restrict__ bhp,
    const bf16* __restrict__ uzuh,
    bf16* bnz, bf16* bnh,
    bf16* hb0, bf16* hb1,
    float* out, unsigned* done) {

    __shared__ float smem[4096];  // 16 KB: scan RED x2 parity / 2 producer halves
    int tid = threadIdx.x;

    if (blockIdx.x < 64) {
        // ---------------- SCAN ROLE ----------------
        int lane = tid & 63, w = tid >> 6;
        int cg = w >> 1, kq = w & 1;
        int r15 = lane & 15, kseg = lane >> 4;
        int cohort = blockIdx.x & 3, blk = blockIdx.x >> 2;
        int h0 = blk * 64 + cg * 16;
        int batch = cohort * 16 + r15;
        int hd0 = blk * 64 + cg * 16 + kseg * 4;

        // permanent A fragments: U rows = this wave's 16 h-cols, its k-half
        bf16x8 aZ[16], aH[16];
        {
            const bf16* azb = uzuh + (size_t)(h0 + r15) * H_DIM + kq * 512 + kseg * 8;
            const bf16* ahb = azb + (size_t)H_DIM * H_DIM;
#pragma unroll
            for (int i = 0; i < 16; ++i) {
                aZ[i] = *reinterpret_cast<const bf16x8*>(azb + i * 32);
                aH[i] = *reinterpret_cast<const bf16x8*>(ahb + i * 32);
            }
        }

#define REDX(par, zh, c, l, j) smem[(par) * 2048 + (zh) * 1024 + (c) * 256 + (l) * 4 + (j)]

        f32x4 hreg = {};
        float bzv[4], bhv[4];

        // pre-loop: kq0 gates chunk 0 and loads bn for t=0 (only kq0 uses bn)
        if (kq == 0) {
            while (__hip_atomic_load(&done[0], __ATOMIC_RELAXED,
                                     __HIP_MEMORY_SCOPE_AGENT) < (unsigned)TILES_PER_CHUNK)
                __builtin_amdgcn_s_sleep(8);
            asm volatile("" ::: "memory");
            u16x4 vz = *reinterpret_cast<const u16x4*>(bnz + (size_t)batch * H_DIM + hd0);
            u16x4 vh = *reinterpret_cast<const u16x4*>(bnh + (size_t)batch * H_DIM + hd0);
#pragma unroll
            for (int j = 0; j < 4; ++j) {
                bzv[j] = __bfloat162float(__ushort_as_bfloat16(vz[j]));
                bhv[j] = __bfloat162float(__ushort_as_bfloat16(vh[j]));
            }
        }

        for (int t = 0; t < T_DIM; ++t) {
            const bf16* hbc = (t & 1) ? hb1 : hb0;
            bf16* hbn = (t & 1) ? hb0 : hb1;

            // expected tag of the data we consume (published at t-1; initial=1)
            int rt = t ? (((t - 1) >> 1) & 1) : 1;
            int expect = rt << 15;

            // poll-load 16 h-fragments (sc0 sc1 LLC-direct) until all tagged
            i32x4 hv[16];
            const bf16* hp = hbc + (size_t)batch * H_DIM + kq * 512 + kseg * 8;
            int tries = 0;
            while (true) {
#pragma unroll
                for (int i = 0; i < 16; ++i)
                    asm volatile("global_load_dwordx4 %0, %1, off sc0 sc1"
                                 : "=v"(hv[i]) : "v"(hp + i * 32));
                asm volatile("s_waitcnt vmcnt(0)" ::: "memory");
                unsigned bad = 0;
#pragma unroll
                for (int i = 0; i < 16; ++i) {
                    bad |= (unsigned)((hv[i][0] ^ expect) & 0x8000);
                    bad |= (unsigned)((hv[i][2] ^ expect) & 0x8000);
                }
                if (!__any(bad != 0u)) break;
                if (++tries > 2) __builtin_amdgcn_s_sleep(1);
            }
            __builtin_amdgcn_sched_barrier(0);

            // strip sign tags (h >= 0, so this restores exact values)
#pragma unroll
            for (int i = 0; i < 16; ++i) {
#pragma unroll
                for (int c = 0; c < 4; ++c)
                    hv[i][c] &= 0x7FFF7FFF;
            }

            f32x4 accZ = {}, accH = {};
#pragma unroll
            for (int i = 0; i < 16; ++i) {
                bf16x8 b = __builtin_bit_cast(bf16x8, hv[i]);
                accZ = __builtin_amdgcn_mfma_f32_16x16x32_bf16(aZ[i], b, accZ, 0, 0, 0);
                accH = __builtin_amdgcn_mfma_f32_16x16x32_bf16(aH[i], b, accH, 0, 0, 0);
            }

            int par = t & 1;
            if (kq == 1) {
                *reinterpret_cast<f32x4*>(&REDX(par, 0, cg, lane, 0)) = accZ;
                *reinterpret_cast<f32x4*>(&REDX(par, 1, cg, lane, 0)) = accH;
            }
            __syncthreads();   // the ONE per-step barrier

            if (kq == 0) {
                accZ += *reinterpret_cast<const f32x4*>(&REDX(par, 0, cg, lane, 0));
                accH += *reinterpret_cast<const f32x4*>(&REDX(par, 1, cg, lane, 0));
#pragma unroll
                for (int j = 0; j < 4; ++j) {
                    float z = 1.f / (1.f + __expf(-(bzv[j] + accZ[j])));
                    float hu = fmaxf(bhv[j] + accH[j], 0.f);
                    hreg[j] = z * hreg[j] + (1.f - z) * hu;
                }
                if (t < T_DIM - 1) {
                    // publish: sign-tag with (t>>1)&1, returning swap -> LLC.
                    unsigned ptag = (unsigned)((t >> 1) & 1) << 15;
                    u16x4 o;
#pragma unroll
                    for (int j = 0; j < 4; ++j)
                        o[j] = (u16)(__bfloat16_as_ushort(__float2bfloat16(hreg[j])) | ptag);
                    u64 old = __hip_atomic_exchange(
                        (u64*)(hbn + (size_t)batch * H_DIM + hd0),
                        __builtin_bit_cast(u64, o),
                        __ATOMIC_RELAXED, __HIP_MEMORY_SCOPE_AGENT);
                    asm volatile("" :: "v"(old));   // keep return live (rule #17)
                }
                // deferred fire-and-forget stores + bn prefetch for t+1
                *reinterpret_cast<f32x4*>(out + (size_t)t * BH + (size_t)batch * H_DIM + hd0) = hreg;
                if (t == T_DIM - 1)
                    *reinterpret_cast<f32x4*>(out + (size_t)T_DIM * BH + (size_t)batch * H_DIM + hd0) = hreg;
                if (t + 1 < T_DIM) {
                    if (((t + 1) & 3) == 0) {
                        // chunk gate for t+1 (off cohort critical path: only
                        // delays this block's own next-step bn availability)
                        while (__hip_atomic_load(&done[(t + 1) >> 2], __ATOMIC_RELAXED,
                                                 __HIP_MEMORY_SCOPE_AGENT) < (unsigned)TILES_PER_CHUNK)
                            __builtin_amdgcn_s_sleep(2);
                        asm volatile("" ::: "memory");
                    }
                    u16x4 vz = *reinterpret_cast<const u16x4*>(
                        bnz + (size_t)(t + 1) * BH + (size_t)batch * H_DIM + hd0);
                    u16x4 vh = *reinterpret_cast<const u16x4*>(
                        bnh + (size_t)(t + 1) * BH + (size_t)batch * H_DIM + hd0);
#pragma unroll
                    for (int j = 0; j < 4; ++j) {
                        bzv[j] = __bfloat162float(__ushort_as_bfloat16(vz[j]));
                        bhv[j] = __bfloat162float(__ushort_as_bfloat16(vh[j]));
                    }
                }
            }
        }
        return;
    }

    // ---------------- PRODUCER ROLE ----------------
    {
        int q = blockIdx.x - 64;           // 0..191
        int sub = tid >> 8;                // half 0/1
        int ltid = tid & 255;
        int lane = ltid & 63;
        int mq = ltid >> 6;                // wave-in-half = batch quarter
        int r15 = lane & 15;
        int kseg = lane >> 4;
        float* sm = smem + sub * 2048;
#define SB(st, wd, tt, col) sm[(st) * 1024 + (wd) * 256 + (tt) * 64 + (col)]

        for (int g = q * 2 + sub; g < NTILES; g += 384) {
            int c = g / TILES_PER_CHUNK;
            int s = g % TILES_PER_CHUNK;
            int t0 = c * 4;

            if (s < 16) {
                // ---- zx tile: bnz[t0..t0+4) cols [h0,h0+64) ----
                int h0 = s * 64;
                const float* xbase = x + (size_t)(t0 * B_DIM + mq * 16 + r15) * I_DIM + kseg * 8;
                f32x4 acc[4][4] = {};
                for (int kk = 0; kk < I_DIM; kk += 32) {
                    bf16x8 b[4];
#pragma unroll
                    for (int nf = 0; nf < 4; ++nf)
                        b[nf] = *reinterpret_cast<const bf16x8*>(
                            wzx + (size_t)(h0 + nf * 16 + r15) * I_DIM + kk + kseg * 8);
#pragma unroll
                    for (int tt = 0; tt < 4; ++tt) {
                        bf16x8 a = cvt8(xbase + (size_t)tt * B_DIM * I_DIM + kk);
#pragma unroll
                        for (int nf = 0; nf < 4; ++nf)
                            acc[tt][nf] = __builtin_amdgcn_mfma_f32_16x16x32_bf16(
                                a, b[nf], acc[tt][nf], 0, 0, 0);
                    }
                }
#pragma unroll
                for (int tt = 0; tt < 4; ++tt)
#pragma unroll
                    for (int nf = 0; nf < 4; ++nf) {
                        float sv = acc[tt][nf][0] + acc[tt][nf][1] + acc[tt][nf][2] + acc[tt][nf][3];
                        float s2 = acc[tt][nf][0] * acc[tt][nf][0] + acc[tt][nf][1] * acc[tt][nf][1] +
                                   acc[tt][nf][2] * acc[tt][nf][2] + acc[tt][nf][3] * acc[tt][nf][3];
                        sv += __shfl_xor(sv, 16); sv += __shfl_xor(sv, 32);
                        s2 += __shfl_xor(s2, 16); s2 += __shfl_xor(s2, 32);
                        if (lane < 16) {
                            SB(0, mq, tt, nf * 16 + r15) = sv;
                            SB(1, mq, tt, nf * 16 + r15) = s2;
                        }
                    }
                __syncthreads();
                int bb = mq * 16 + kseg * 4;
#pragma unroll
                for (int tt = 0; tt < 4; ++tt)
#pragma unroll
                    for (int nf = 0; nf < 4; ++nf) {
                        int col = nf * 16 + r15;
                        float sv = SB(0, 0, tt, col) + SB(0, 1, tt, col) + SB(0, 2, tt, col) + SB(0, 3, tt, col);
                        float s2 = SB(1, 0, tt, col) + SB(1, 1, tt, col) + SB(1, 2, tt, col) + SB(1, 3, tt, col);
                        float mu = sv * (1.f / B_DIM);
                        float var = s2 * (1.f / B_DIM) - mu * mu;
                        int h = h0 + col;
                        float sc = rsqrtf(var + BN_EPS) * gzp[h];
                        float sh = bzp[h] - mu * sc;
#pragma unroll
                        for (int j = 0; j < 4; ++j)
                            bnz[(size_t)((t0 + tt) * B_DIM + bb + j) * H_DIM + h] =
                                __float2bfloat16(acc[tt][nf][j] * sc + sh);
                    }
            } else {
                // ---- s tile: bnh[t0..t0+4) cols [h0,h0+16) ----
                int h0 = (s - 16) * 16;
                int u0 = h0 * U_DIM;
                const float* xbase = x + (size_t)(t0 * B_DIM + mq * 16 + r15) * I_DIM + kseg * 8;
                f32x4 acc[4][8] = {};
                for (int kk = 0; kk < I_DIM; kk += 32) {
                    bf16x8 b[8];
#pragma unroll
                    for (int nf = 0; nf < 8; ++nf)
                        b[nf] = *reinterpret_cast<const bf16x8*>(
                            whx + (size_t)(u0 + nf * 16 + r15) * I_DIM + kk + kseg * 8);
#pragma unroll
                    for (int tt = 0; tt < 4; ++tt) {
                        bf16x8 a = cvt8(xbase + (size_t)tt * B_DIM * I_DIM + kk);
#pragma unroll
                        for (int nf = 0; nf < 8; ++nf)
                            acc[tt][nf] = __builtin_amdgcn_mfma_f32_16x16x32_bf16(
                                a, b[nf], acc[tt][nf], 0, 0, 0);
                    }
                }
                int uloc = r15 & 7;
#pragma unroll
                for (int nf = 0; nf < 8; ++nf) {
                    int ucol = u0 + nf * 16 + r15;
                    float wd = wdiag[ucol];
                    float bu = b_unit[ucol];
#pragma unroll
                    for (int tt = 0; tt < 4; ++tt)
#pragma unroll
                        for (int j = 0; j < 4; ++j) {
                            float v = fmaxf(acc[tt][nf][j] + bu, 0.f) * wd;
                            v += __shfl_xor(v, 1);
                            v += __shfl_xor(v, 2);
                            v += __shfl_xor(v, 4);
                            acc[tt][nf][j] = v;
                        }
                }
#pragma unroll
                for (int tt = 0; tt < 4; ++tt)
#pragma unroll
                    for (int nf = 0; nf < 8; ++nf) {
                        float sv = 0.f, s2 = 0.f;
                        if (uloc == 0) {
#pragma unroll
                            for (int j = 0; j < 4; ++j) {
                                sv += acc[tt][nf][j];
                                s2 += acc[tt][nf][j] * acc[tt][nf][j];
                            }
                        }
                        sv += __shfl_xor(sv, 16); sv += __shfl_xor(sv, 32);
                        s2 += __shfl_xor(s2, 16); s2 += __shfl_xor(s2, 32);
                        if (lane == 0 || lane == 8) {
                            int col = nf * 2 + (r15 >> 3);
                            SB(0, mq, tt, col) = sv;
                            SB(1, mq, tt, col) = s2;
                        }
                    }
                __syncthreads();
                int bb = mq * 16 + kseg * 4;
#pragma unroll
                for (int tt = 0; tt < 4; ++tt)
#pragma unroll
                    for (int nf = 0; nf < 8; ++nf) {
                        int col = nf * 2 + (r15 >> 3);
                        float sv = SB(0, 0, tt, col) + SB(0, 1, tt, col) + SB(0, 2, tt, col) + SB(0, 3, tt, col);
                        float s2 = SB(1, 0, tt, col) + SB(1, 1, tt, col) + SB(1, 2, tt, col) + SB(1, 3, tt, col);
                        float mu = sv * (1.f / B_DIM);
                        float var = s2 * (1.f / B_DIM) - mu * mu;
                        int h = h0 + col;
                        float sc = rsqrtf(var + BN_EPS) * ghp[h];
                        float sh = bhp[h] - mu * sc;
                        if (uloc == 0) {
#pragma unroll
                            for (int j = 0; j < 4; ++j)
                                bnh[(size_t)((t0 + tt) * B_DIM + bb + j) * H_DIM + h] =
                                    __float2bfloat16(acc[tt][nf][j] * sc + sh);
                        }
                    }
            }
            __syncthreads();   // drain all waves' bn stores + LDS WAR before next tile
            if (ltid == 0)
                __hip_atomic_fetch_add(&done[c], 1u, __ATOMIC_RELEASE, __HIP_MEMORY_SCOPE_AGENT);
        }
    }
}

// ---------------- workspace layout (bytes) ----------------
#define OFF_WZX   ((size_t)16777216)              // 1 MB
#define OFF_WHX   ((size_t)17825792)              // 8 MB
#define OFF_UZUH  ((size_t)26214400)              // 4 MB
#define OFF_WDIAG ((size_t)30408704)              // 32 KB
#define OFF_BNZ   ((size_t)30441472)              // 32 MB
#define OFF_BNH   ((size_t)63995904)              // 32 MB
#define OFF_DONE  ((size_t)97615872)              // 4 KB chunk counters
#define OFF_HB0   ((size_t)98074624)              // 128 KB
#define OFF_HB1   ((size_t)98205696)              // 128 KB

extern "C" void kernel_launch(void* const* d_in, const int* in_sizes, int n_in,
                              void* d_out, int out_size, void* d_ws, size_t ws_size,
                              hipStream_t stream) {
    const float* x      = (const float*)d_in[0];
    const float* Wzx    = (const float*)d_in[1];
    const float* Whx    = (const float*)d_in[2];
    const float* Uz     = (const float*)d_in[3];
    const float* Uh     = (const float*)d_in[4];
    const float* b_unit = (const float*)d_in[5];
    const float* Wh_in  = (const float*)d_in[6];
    const float* gz     = (const float*)d_in[7];
    const float* bz     = (const float*)d_in[8];
    const float* gh     = (const float*)d_in[9];
    const float* bh     = (const float*)d_in[10];
    const float* mask   = (const float*)d_in[11];

    char* ws = (char*)d_ws;
    bf16*     wzx_b = (bf16*)(ws + OFF_WZX);
    bf16*     whx_b = (bf16*)(ws + OFF_WHX);
    bf16*     uzuh  = (bf16*)(ws + OFF_UZUH);
    float*    wdiag = (float*)(ws + OFF_WDIAG);
    bf16*     bnz   = (bf16*)(ws + OFF_BNZ);
    bf16*     bnh   = (bf16*)(ws + OFF_BNH);
    unsigned* done  = (unsigned*)(ws + OFF_DONE);
    bf16*     hb0   = (bf16*)(ws + OFF_HB0);
    bf16*     hb1   = (bf16*)(ws + OFF_HB1);

    float* out = (float*)d_out;

    // 1. weight converts (x is consumed as f32 directly by producers)
    k_cvt4<<<512, 256, 0, stream>>>(Wzx, (u16*)wzx_b, H_DIM * I_DIM / 4);
    k_cvt4<<<2048, 256, 0, stream>>>(Whx, (u16*)whx_b, U_DIM * H_DIM * I_DIM / 4);
    k_pack_uzuh<<<2048, 256, 0, stream>>>(Uz, Uh, (u16*)uzuh);
    k_wdiag<<<(H_DIM * U_DIM + 255) / 256, 256, 0, stream>>>(Wh_in, mask, wdiag);

    // 2. init h buffers to tagged -0.0 (tag=1, value 0); done = 0
    k_init_tag<<<128, 256, 0, stream>>>((u64*)hb0, BH / 4);
    k_init_tag<<<128, 256, 0, stream>>>((u64*)hb1, BH / 4);
    hipMemsetAsync(done, 0, 4096, stream);

    // 3. fused producer (GEMM+BN) + consumer (scan) mega-kernel
    k_mega<<<256, 512, 0, stream>>>(x, wzx_b, whx_b, b_unit, wdiag,
                                    gz, bz, gh, bh, uzuh,
                                    bnz, bnh, hb0, hb1, out, done);
}

// Round 18
// 1788.115 us; speedup vs baseline: 1.9315x; 1.9315x over previous
//
#include <hip/hip_runtime.h>
#include <hip/hip_bf16.h>

// Problem dims
#define T_DIM 256
#define B_DIM 64
#define I_DIM 512
#define H_DIM 1024
#define U_DIM 8
#define BN_EPS 1e-5f
#define BH (B_DIM * H_DIM)
#define NCHUNK 64          // 4 timesteps per chunk
#define TILES_PER_CHUNK 80 // 16 zx + 64 s
#define NTILES 5120        // 64 chunks * 80

typedef __bf16 bf16x8 __attribute__((ext_vector_type(8)));
typedef float f32x4 __attribute__((ext_vector_type(4)));
typedef int i32x4 __attribute__((ext_vector_type(4)));
typedef unsigned short u16;
typedef u16 u16x4 __attribute__((ext_vector_type(4)));
typedef unsigned long long u64;
using bf16 = __hip_bfloat16;

// ---------------- conversion / packing kernels (vectorized) ----------------

__global__ void k_cvt4(const float* __restrict__ in, u16* __restrict__ out, int n4) {
    int i = blockIdx.x * blockDim.x + threadIdx.x;
    int stride = gridDim.x * blockDim.x;
    for (; i < n4; i += stride) {
        f32x4 v = *reinterpret_cast<const f32x4*>(in + (size_t)i * 4);
        u16x4 o;
#pragma unroll
        for (int j = 0; j < 4; ++j)
            o[j] = __bfloat16_as_ushort(__float2bfloat16(v[j]));
        *reinterpret_cast<u16x4*>(out + (size_t)i * 4) = o;
    }
}

// pack [Uz; Uh] into one [2048,1024] bf16 K-major matrix (4-elem chunks)
__global__ void k_pack_uzuh(const float* __restrict__ Uz, const float* __restrict__ Uh,
                            u16* __restrict__ out) {
    int i = blockIdx.x * 256 + threadIdx.x;
    int stride = gridDim.x * 256;
    int n4 = 2 * H_DIM * H_DIM / 4;
    for (; i < n4; i += stride) {
        int c = i * 4;
        int n = c >> 10, k = c & 1023;
        const float* src = (n < H_DIM) ? (Uz + (size_t)n * H_DIM + k)
                                       : (Uh + (size_t)(n - H_DIM) * H_DIM + k);
        f32x4 v = *reinterpret_cast<const f32x4*>(src);
        u16x4 o;
#pragma unroll
        for (int j = 0; j < 4; ++j)
            o[j] = __bfloat16_as_ushort(__float2bfloat16(v[j]));
        *reinterpret_cast<u16x4*>(out + c) = o;
    }
}

// extract block-diagonal of Wm = Wh_in * mask: wdiag[h*8+u] = Wm[h][h*8+u]
__global__ void k_wdiag(const float* __restrict__ Wh_in, const float* __restrict__ mask,
                        float* __restrict__ wdiag) {
    int idx = blockIdx.x * 256 + threadIdx.x;
    if (idx < H_DIM * U_DIM) {
        int h = idx >> 3;
        size_t col = (size_t)h * (H_DIM * U_DIM) + idx;
        wdiag[idx] = Wh_in[col] * mask[col];
    }
}

// load 8 consecutive f32, convert to bf16x8 in-register (same RTN as k_cvt4)
__device__ __forceinline__ bf16x8 cvt8(const float* p) {
    f32x4 a = *reinterpret_cast<const f32x4*>(p);
    f32x4 b = *reinterpret_cast<const f32x4*>(p + 4);
    union { u16 u[8]; bf16x8 v; } r;
#pragma unroll
    for (int j = 0; j < 4; ++j) {
        r.u[j]     = __bfloat16_as_ushort(__float2bfloat16(a[j]));
        r.u[4 + j] = __bfloat16_as_ushort(__float2bfloat16(b[j]));
    }
    return r.v;
}

// ==================== MEGA KERNEL ====================
// 256 blocks x 512 threads (R7-proven static roles; NO placement assumptions).
//  blocks 0..63  : scan (4 cohorts x 16 blocks). Converged protocol:
//    (1) chunk gate folded into the PREVIOUS step's flag poll (overlapped
//        LLC RTs; boundary steps skip the dedicated gate poll + barrier),
//    (2) boundary bn loads issued AFTER the h loads (latency overlap),
//    (3) pure-spin flag poll (no s_sleep quantization).
//    PUBLISH: returning global_atomic_swap (relaxed, agent) -> vmcnt retire =
//      LLC arrival -> __syncthreads -> relaxed flag store. CONSUME: LLC-direct
//      sc0 sc1 loads staged 16-deep, no acquire fence. (R10/R11-validated.)
//  blocks 64..255: persistent producers (R7 verbatim): 5120 GEMM+BN tiles,
//    chunk-major, release-atomicAdd(done[c]) per tile (wbl2 publishes bn).

__global__ __launch_bounds__(512, 2) void k_mega(
    const float* __restrict__ x,
    const bf16* __restrict__ wzx, const bf16* __restrict__ whx,
    const float* __restrict__ b_unit, const float* __restrict__ wdiag,
    const float* __restrict__ gzp, const float* __restrict__ bzp,
    const float* __restrict__ ghp, const float* __restrict__ bhp,
    const bf16* __restrict__ uzuh,
    bf16* bnz, bf16* bnh,
    bf16* hb0, bf16* hb1,
    float* out, unsigned* flags, unsigned* done) {

    __shared__ float smem[4096];  // 16 KB: scan red (8K) / 2 producer halves (8K each)
    int tid = threadIdx.x;

    if (blockIdx.x < 64) {
        // ---------------- SCAN ROLE ----------------
        int lane = tid & 63, w = tid >> 6;
        int cg = w >> 1, kq = w & 1;
        int r15 = lane & 15, kseg = lane >> 4;
        int cohort = blockIdx.x & 3, blk = blockIdx.x >> 2;
        int h0 = blk * 64 + cg * 16;
        int batch = cohort * 16 + r15;
        int hd0 = blk * 64 + cg * 16 + kseg * 4;

        // permanent A fragments: U rows = this wave's 16 h-cols, its k-half
        bf16x8 aZ[16], aH[16];
        {
            const bf16* azb = uzuh + (size_t)(h0 + r15) * H_DIM + kq * 512 + kseg * 8;
            const bf16* ahb = azb + (size_t)H_DIM * H_DIM;
#pragma unroll
            for (int i = 0; i < 16; ++i) {
                aZ[i] = *reinterpret_cast<const bf16x8*>(azb + i * 32);
                aH[i] = *reinterpret_cast<const bf16x8*>(ahb + i * 32);
            }
        }

#define RED(zh, c, l, j) smem[(zh) * 1024 + (c) * 256 + (l) * 4 + (j)]

        f32x4 hreg = {};
        float bzv[4], bhv[4];

        for (int t = 0; t < T_DIM; ++t) {
            const bf16* hbc = (t & 1) ? hb1 : hb0;
            bf16* hbn = (t & 1) ? hb0 : hb1;

            if (t == 0) {
                // one-time gate for chunk 0 (later gates fold into flag polls)
                if (w == 0) {
                    while (__hip_atomic_load(&done[0], __ATOMIC_RELAXED,
                                             __HIP_MEMORY_SCOPE_AGENT) < (unsigned)TILES_PER_CHUNK)
                        __builtin_amdgcn_s_sleep(8);
                }
                __syncthreads();
                asm volatile("" ::: "memory");
            }

            // issue all 16 h-fragment loads FIRST (sc0 sc1 LLC-direct,
            // validated R4/R6/R10), then boundary bn loads (latency overlap),
            // then one vmcnt(0) + sched_barrier(0) (rule #18).
            i32x4 hv[16];
            const bf16* hp = hbc + (size_t)batch * H_DIM + kq * 512 + kseg * 8;
#pragma unroll
            for (int i = 0; i < 16; ++i)
                asm volatile("global_load_dwordx4 %0, %1, off sc0 sc1"
                             : "=v"(hv[i]) : "v"(hp + i * 32));
            if ((t & 3) == 0 && kq == 0) {
                // boundary bn loads (chunk gate already confirmed: t==0 above,
                // else during step t-1's flag poll, sequenced by sync#3)
                u16x4 vz = *reinterpret_cast<const u16x4*>(
                    bnz + (size_t)t * BH + (size_t)batch * H_DIM + hd0);
                u16x4 vh = *reinterpret_cast<const u16x4*>(
                    bnh + (size_t)t * BH + (size_t)batch * H_DIM + hd0);
#pragma unroll
                for (int j = 0; j < 4; ++j) {
                    bzv[j] = __bfloat162float(__ushort_as_bfloat16(vz[j]));
                    bhv[j] = __bfloat162float(__ushort_as_bfloat16(vh[j]));
                }
            }
            asm volatile("s_waitcnt vmcnt(0)" ::: "memory");
            __builtin_amdgcn_sched_barrier(0);

            f32x4 accZ = {}, accH = {};
#pragma unroll
            for (int i = 0; i < 16; ++i) {
                bf16x8 b = __builtin_bit_cast(bf16x8, hv[i]);
                accZ = __builtin_amdgcn_mfma_f32_16x16x32_bf16(aZ[i], b, accZ, 0, 0, 0);
                accH = __builtin_amdgcn_mfma_f32_16x16x32_bf16(aH[i], b, accH, 0, 0, 0);
            }

            if (kq == 1) {
                *reinterpret_cast<f32x4*>(&RED(0, cg, lane, 0)) = accZ;
                *reinterpret_cast<f32x4*>(&RED(1, cg, lane, 0)) = accH;
            }
            __syncthreads();   // sync#1

            if (kq == 0) {
                accZ += *reinterpret_cast<const f32x4*>(&RED(0, cg, lane, 0));
                accH += *reinterpret_cast<const f32x4*>(&RED(1, cg, lane, 0));
#pragma unroll
                for (int j = 0; j < 4; ++j) {
                    float z = 1.f / (1.f + __expf(-(bzv[j] + accZ[j])));
                    float hu = fmaxf(bhv[j] + accH[j], 0.f);
                    hreg[j] = z * hreg[j] + (1.f - z) * hu;
                }
                // h publish: RETURNING atomic swap (relaxed, agent). Live
                // return forces vmcnt retire = LLC arrival (R11-proven).
                u16x4 o;
#pragma unroll
                for (int j = 0; j < 4; ++j)
                    o[j] = __bfloat16_as_ushort(__float2bfloat16(hreg[j]));
                u64 old = __hip_atomic_exchange(
                    (u64*)(hbn + (size_t)batch * H_DIM + hd0),
                    __builtin_bit_cast(u64, o),
                    __ATOMIC_RELAXED, __HIP_MEMORY_SCOPE_AGENT);
                asm volatile("" :: "v"(old));   // keep return live (rule #17)
            }

            if (t < T_DIM - 1) {
                __syncthreads();   // sync#2: vmcnt(0) -> all swaps at LLC
                if (w == 0) {
                    if (lane == 0)
                        __hip_atomic_store(&flags[(size_t)(cohort * 16 + blk) * 16],
                                           (unsigned)(t + 1),
                                           __ATOMIC_RELAXED, __HIP_MEMORY_SCOPE_AGENT);
                    // pure-spin poll: 16 cohort flags AND (if next step is a
                    // chunk boundary) the producers' done counter — both loads
                    // issued per iteration so their LLC RTs overlap.
                    bool ng = ((t + 1) & 3) == 0;
                    unsigned cnx = (unsigned)((t + 1) >> 2);
                    while (true) {
                        unsigned v = __hip_atomic_load(
                            &flags[(size_t)(cohort * 16 + r15) * 16],
                            __ATOMIC_RELAXED, __HIP_MEMORY_SCOPE_AGENT);
                        unsigned g = ng ? __hip_atomic_load(&done[cnx],
                                              __ATOMIC_RELAXED, __HIP_MEMORY_SCOPE_AGENT)
                                        : (unsigned)TILES_PER_CHUNK;
                        if (!__any(v <= (unsigned)t) && g >= (unsigned)TILES_PER_CHUNK)
                            break;
                    }
                    // NO acquire fence: h reads are LLC-direct (sc0 sc1); bn
                    // lines are first-touch (release-wbl2 published).
                }
                __syncthreads();   // sync#3
            }

            if (kq == 0) {
                // deferred fire-and-forget stores + intra-chunk bn prefetch
                *reinterpret_cast<f32x4*>(out + (size_t)t * BH + (size_t)batch * H_DIM + hd0) = hreg;
                if (t == T_DIM - 1)
                    *reinterpret_cast<f32x4*>(out + (size_t)T_DIM * BH + (size_t)batch * H_DIM + hd0) = hreg;
                if (t + 1 < T_DIM && ((t + 1) & 3) != 0) {
                    u16x4 vz = *reinterpret_cast<const u16x4*>(
                        bnz + (size_t)(t + 1) * BH + (size_t)batch * H_DIM + hd0);
                    u16x4 vh = *reinterpret_cast<const u16x4*>(
                        bnh + (size_t)(t + 1) * BH + (size_t)batch * H_DIM + hd0);
#pragma unroll
                    for (int j = 0; j < 4; ++j) {
                        bzv[j] = __bfloat162float(__ushort_as_bfloat16(vz[j]));
                        bhv[j] = __bfloat162float(__ushort_as_bfloat16(vh[j]));
                    }
                }
            }
        }
        return;
    }

    // ---------------- PRODUCER ROLE ----------------
    {
        int q = blockIdx.x - 64;           // 0..191
        int sub = tid >> 8;                // half 0/1
        int ltid = tid & 255;
        int lane = ltid & 63;
        int mq = ltid >> 6;                // wave-in-half = batch quarter
        int r15 = lane & 15;
        int kseg = lane >> 4;
        float* sm = smem + sub * 2048;
#define SB(st, wd, tt, col) sm[(st) * 1024 + (wd) * 256 + (tt) * 64 + (col)]

        for (int g = q * 2 + sub; g < NTILES; g += 384) {
            int c = g / TILES_PER_CHUNK;
            int s = g % TILES_PER_CHUNK;
            int t0 = c * 4;

            if (s < 16) {
                // ---- zx tile: bnz[t0..t0+4) cols [h0,h0+64) ----
                int h0 = s * 64;
                const float* xbase = x + (size_t)(t0 * B_DIM + mq * 16 + r15) * I_DIM + kseg * 8;
                f32x4 acc[4][4] = {};
                for (int kk = 0; kk < I_DIM; kk += 32) {
                    bf16x8 b[4];
#pragma unroll
                    for (int nf = 0; nf < 4; ++nf)
                        b[nf] = *reinterpret_cast<const bf16x8*>(
                            wzx + (size_t)(h0 + nf * 16 + r15) * I_DIM + kk + kseg * 8);
#pragma unroll
                    for (int tt = 0; tt < 4; ++tt) {
                        bf16x8 a = cvt8(xbase + (size_t)tt * B_DIM * I_DIM + kk);
#pragma unroll
                        for (int nf = 0; nf < 4; ++nf)
                            acc[tt][nf] = __builtin_amdgcn_mfma_f32_16x16x32_bf16(
                                a, b[nf], acc[tt][nf], 0, 0, 0);
                    }
                }
#pragma unroll
                for (int tt = 0; tt < 4; ++tt)
#pragma unroll
                    for (int nf = 0; nf < 4; ++nf) {
                        float sv = acc[tt][nf][0] + acc[tt][nf][1] + acc[tt][nf][2] + acc[tt][nf][3];
                        float s2 = acc[tt][nf][0] * acc[tt][nf][0] + acc[tt][nf][1] * acc[tt][nf][1] +
                                   acc[tt][nf][2] * acc[tt][nf][2] + acc[tt][nf][3] * acc[tt][nf][3];
                        sv += __shfl_xor(sv, 16); sv += __shfl_xor(sv, 32);
                        s2 += __shfl_xor(s2, 16); s2 += __shfl_xor(s2, 32);
                        if (lane < 16) {
                            SB(0, mq, tt, nf * 16 + r15) = sv;
                            SB(1, mq, tt, nf * 16 + r15) = s2;
                        }
                    }
                __syncthreads();
                int bb = mq * 16 + kseg * 4;
#pragma unroll
                for (int tt = 0; tt < 4; ++tt)
#pragma unroll
                    for (int nf = 0; nf < 4; ++nf) {
                        int col = nf * 16 + r15;
                        float sv = SB(0, 0, tt, col) + SB(0, 1, tt, col) + SB(0, 2, tt, col) + SB(0, 3, tt, col);
                        float s2 = SB(1, 0, tt, col) + SB(1, 1, tt, col) + SB(1, 2, tt, col) + SB(1, 3, tt, col);
                        float mu = sv * (1.f / B_DIM);
                        float var = s2 * (1.f / B_DIM) - mu * mu;
                        int h = h0 + col;
                        float sc = rsqrtf(var + BN_EPS) * gzp[h];
                        float sh = bzp[h] - mu * sc;
#pragma unroll
                        for (int j = 0; j < 4; ++j)
                            bnz[(size_t)((t0 + tt) * B_DIM + bb + j) * H_DIM + h] =
                                __float2bfloat16(acc[tt][nf][j] * sc + sh);
                    }
            } else {
                // ---- s tile: bnh[t0..t0+4) cols [h0,h0+16) ----
                int h0 = (s - 16) * 16;
                int u0 = h0 * U_DIM;
                const float* xbase = x + (size_t)(t0 * B_DIM + mq * 16 + r15) * I_DIM + kseg * 8;
                f32x4 acc[4][8] = {};
                for (int kk = 0; kk < I_DIM; kk += 32) {
                    bf16x8 b[8];
#pragma unroll
                    for (int nf = 0; nf < 8; ++nf)
                        b[nf] = *reinterpret_cast<const bf16x8*>(
                            whx + (size_t)(u0 + nf * 16 + r15) * I_DIM + kk + kseg * 8);
#pragma unroll
                    for (int tt = 0; tt < 4; ++tt) {
                        bf16x8 a = cvt8(xbase + (size_t)tt * B_DIM * I_DIM + kk);
#pragma unroll
                        for (int nf = 0; nf < 8; ++nf)
                            acc[tt][nf] = __builtin_amdgcn_mfma_f32_16x16x32_bf16(
                                a, b[nf], acc[tt][nf], 0, 0, 0);
                    }
                }
                int uloc = r15 & 7;
#pragma unroll
                for (int nf = 0; nf < 8; ++nf) {
                    int ucol = u0 + nf * 16 + r15;
                    float wd = wdiag[ucol];
                    float bu = b_unit[ucol];
#pragma unroll
                    for (int tt = 0; tt < 4; ++tt)
#pragma unroll
                        for (int j = 0; j < 4; ++j) {
                            float v = fmaxf(acc[tt][nf][j] + bu, 0.f) * wd;
                            v += __shfl_xor(v, 1);
                            v += __shfl_xor(v, 2);
                            v += __shfl_xor(v, 4);
                            acc[tt][nf][j] = v;
                        }
                }
#pragma unroll
                for (int tt = 0; tt < 4; ++tt)
#pragma unroll
                    for (int nf = 0; nf < 8; ++nf) {
                        float sv = 0.f, s2 = 0.f;
                        if (uloc == 0) {
#pragma unroll
                            for (int j = 0; j < 4; ++j) {
                                sv += acc[tt][nf][j];
                                s2 += acc[tt][nf][j] * acc[tt][nf][j];
                            }
                        }
                        sv += __shfl_xor(sv, 16); sv += __shfl_xor(sv, 32);
                        s2 += __shfl_xor(s2, 16); s2 += __shfl_xor(s2, 32);
                        if (lane == 0 || lane == 8) {
                            int col = nf * 2 + (r15 >> 3);
                            SB(0, mq, tt, col) = sv;
                            SB(1, mq, tt, col) = s2;
                        }
                    }
                __syncthreads();
                int bb = mq * 16 + kseg * 4;
#pragma unroll
                for (int tt = 0; tt < 4; ++tt)
#pragma unroll
                    for (int nf = 0; nf < 8; ++nf) {
                        int col = nf * 2 + (r15 >> 3);
                        float sv = SB(0, 0, tt, col) + SB(0, 1, tt, col) + SB(0, 2, tt, col) + SB(0, 3, tt, col);
                        float s2 = SB(1, 0, tt, col) + SB(1, 1, tt, col) + SB(1, 2, tt, col) + SB(1, 3, tt, col);
                        float mu = sv * (1.f / B_DIM);
                        float var = s2 * (1.f / B_DIM) - mu * mu;
                        int h = h0 + col;
                        float sc = rsqrtf(var + BN_EPS) * ghp[h];
                        float sh = bhp[h] - mu * sc;
                        if (uloc == 0) {
#pragma unroll
                            for (int j = 0; j < 4; ++j)
                                bnh[(size_t)((t0 + tt) * B_DIM + bb + j) * H_DIM + h] =
                                    __float2bfloat16(acc[tt][nf][j] * sc + sh);
                        }
                    }
            }
            __syncthreads();   // drain all waves' bn stores + LDS WAR before next tile
            if (ltid == 0)
                __hip_atomic_fetch_add(&done[c], 1u, __ATOMIC_RELEASE, __HIP_MEMORY_SCOPE_AGENT);
        }
    }
}

// ---------------- workspace layout (bytes) ----------------
#define OFF_WZX   ((size_t)16777216)              // 1 MB
#define OFF_WHX   ((size_t)17825792)              // 8 MB
#define OFF_UZUH  ((size_t)26214400)              // 4 MB
#define OFF_WDIAG ((size_t)30408704)              // 32 KB
#define OFF_BNZ   ((size_t)30441472)              // 32 MB
#define OFF_BNH   ((size_t)63995904)              // 32 MB
#define OFF_BAR   ((size_t)97550336)              // 16 KB flag array
#define OFF_DONE  ((size_t)97615872)              // 4 KB chunk counters
#define OFF_HB0   ((size_t)98074624)              // 128 KB
#define OFF_HB1   ((size_t)98205696)              // 128 KB

extern "C" void kernel_launch(void* const* d_in, const int* in_sizes, int n_in,
                              void* d_out, int out_size, void* d_ws, size_t ws_size,
                              hipStream_t stream) {
    const float* x      = (const float*)d_in[0];
    const float* Wzx    = (const float*)d_in[1];
    const float* Whx    = (const float*)d_in[2];
    const float* Uz     = (const float*)d_in[3];
    const float* Uh     = (const float*)d_in[4];
    const float* b_unit = (const float*)d_in[5];
    const float* Wh_in  = (const float*)d_in[6];
    const float* gz     = (const float*)d_in[7];
    const float* bz     = (const float*)d_in[8];
    const float* gh     = (const float*)d_in[9];
    const float* bh     = (const float*)d_in[10];
    const float* mask   = (const float*)d_in[11];

    char* ws = (char*)d_ws;
    bf16*     wzx_b = (bf16*)(ws + OFF_WZX);
    bf16*     whx_b = (bf16*)(ws + OFF_WHX);
    bf16*     uzuh  = (bf16*)(ws + OFF_UZUH);
    float*    wdiag = (float*)(ws + OFF_WDIAG);
    bf16*     bnz   = (bf16*)(ws + OFF_BNZ);
    bf16*     bnh   = (bf16*)(ws + OFF_BNH);
    unsigned* flags = (unsigned*)(ws + OFF_BAR);
    unsigned* done  = (unsigned*)(ws + OFF_DONE);
    bf16*     hb0   = (bf16*)(ws + OFF_HB0);
    bf16*     hb1   = (bf16*)(ws + OFF_HB1);

    float* out = (float*)d_out;

    // 1. weight converts (x is consumed as f32 directly by producers)
    k_cvt4<<<512, 256, 0, stream>>>(Wzx, (u16*)wzx_b, H_DIM * I_DIM / 4);
    k_cvt4<<<2048, 256, 0, stream>>>(Whx, (u16*)whx_b, U_DIM * H_DIM * I_DIM / 4);
    k_pack_uzuh<<<2048, 256, 0, stream>>>(Uz, Uh, (u16*)uzuh);
    k_wdiag<<<(H_DIM * U_DIM + 255) / 256, 256, 0, stream>>>(Wh_in, mask, wdiag);

    // 2. init h = 0, flags = 0, done = 0
    hipMemsetAsync(hb0, 0, (size_t)BH * sizeof(bf16), stream);
    hipMemsetAsync(flags, 0, 16384, stream);
    hipMemsetAsync(done, 0, 4096, stream);

    // 3. fused producer (GEMM+BN) + consumer (scan) mega-kernel
    k_mega<<<256, 512, 0, stream>>>(x, wzx_b, whx_b, b_unit, wdiag,
                                    gz, bz, gh, bh, uzuh,
                                    bnz, bnh, hb0, hb1, out, flags, done);
}